// Round 5
// baseline (134.521 us; speedup 1.0000x reference)
//
#include <hip/hip_runtime.h>
#include <math.h>

#define B_    32
#define CIN   16
#define T_    2048
#define NE    8
#define NG    8
#define CPG   16
#define HID   128
#define KW    5
#define EPS_  1e-5f

#define ROWB  24      // bf16 elems per xT row (16 used + pad) -> 48B rows
#define HLF   1024    // T per block
#define NROWH 1029    // 2 front + 1024 + 3 back halo rows
#define NTH   512

typedef float f32x4 __attribute__((ext_vector_type(4)));
typedef short s16x8 __attribute__((ext_vector_type(8)));

// ws layout (floats)
#define WS_R0P   0        // [2][32][128] GAP partials per half
#define WS_GW    8192     // [64] gate weights
#define WS_GI    8256     // [64] gate indices (int)
#define WS_STR   8320     // [32][8][2 half][2] router stats
#define WS_STE   9344     // [32][8][3 slot][2 half][2] expert stats

__device__ __forceinline__ float gelu_fast(float y) {
    float u = 0.7978845608028654f * (y + 0.044715f * y * y * y);
    float au = fabsf(u);
    float e = __expf(2.0f * au);
    float th = copysignf(1.0f - 2.0f / (e + 1.0f), u);
    return 0.5f * y * (1.0f + th);
}

__device__ __forceinline__ float gelu_erf(float y) {
    return 0.5f * y * (1.0f + erff(y * 0.70710678118654752440f));
}

__device__ __forceinline__ short bf16r(float f) {
    unsigned u = __builtin_bit_cast(unsigned, f);
    u = u + 0x7FFFu + ((u >> 16) & 1u);   // round-to-nearest-even
    return (short)(u >> 16);
}

// stage half of x[b] -> bf16 transposed xs[lr][ci], t_global = base-2+lr
__device__ __forceinline__ void stage_half(const float* __restrict__ xb,
                                           int base, short* __restrict__ xs,
                                           int tid)
{
    // interior rows lr in [2,1026): aligned f32x4 chunks, t = base + cr*4
    for (int i = tid; i < CIN * 256; i += NTH) {
        int ci = i >> 8, cr = i & 255;
        int t = base + cr * 4;
        f32x4 v = *(const f32x4*)(xb + ci * T_ + t);
        short* p = xs + (cr * 4 + 2) * ROWB + ci;
        p[0]        = bf16r(v.x);
        p[ROWB]     = bf16r(v.y);
        p[2 * ROWB] = bf16r(v.z);
        p[3 * ROWB] = bf16r(v.w);
    }
    // halo rows lr in {0,1,1026,1027,1028}
    if (tid < 80) {
        int r = tid >> 4, ci = tid & 15;
        int lr = (r < 2) ? r : 1024 + r;
        int t = base - 2 + lr;
        float v = (t >= 0 && t < T_) ? xb[ci * T_ + t] : 0.0f;
        xs[lr * ROWB + ci] = bf16r(v);
    }
}

// load one A fragment trio (3 shift-pairs) for a 16-co weight panel
__device__ __forceinline__ void load_afrag(const float* __restrict__ wb,
                                           int n, int cib, int s_, s16x8* afr)
{
    #pragma unroll
    for (int p = 0; p < 3; ++p) {
        int sh = 2 * p + s_;
        s16x8 a;
        if (sh < 5) {
            const float* wp = wb + (size_t)n * (CIN * KW) + cib * KW + sh;
            #pragma unroll
            for (int j = 0; j < 8; ++j) a[j] = bf16r(wp[j * KW]);
        } else {
            #pragma unroll
            for (int j = 0; j < 8; ++j) a[j] = 0;
        }
        afr[p] = a;
    }
}

// ---------------------------------------------------------------------------
// K1a: router conv stats partials per (b, g, half)
// ---------------------------------------------------------------------------
__global__ __launch_bounds__(512, 4) void router_stats_kernel(
    const float* __restrict__ x, const float* __restrict__ rw,
    float* __restrict__ ws)
{
    __shared__ short xs[NROWH * ROWB];
    __shared__ float redS[8], redQ[8];

    const int bh = blockIdx.x, g = blockIdx.y;
    const int b = bh >> 1, half = bh & 1, base = half * HLF;
    const int tid = threadIdx.x;
    const int l = tid & 63, wv = tid >> 6;
    const int n = l & 15, grp = l >> 4;
    const int s_ = grp >> 1, cib = (grp & 1) * 8;

    stage_half(x + (size_t)b * CIN * T_, base, xs, tid);
    s16x8 afr[3];
    load_afrag(rw + (size_t)g * CPG * (CIN * KW), n, cib, s_, afr);
    __syncthreads();

    float sA = 0.f, qA = 0.f;
    for (int tile = 0; tile < 8; ++tile) {
        const int t0 = (wv * 8 + tile) * 16;
        s16x8 bf0 = *(const s16x8*)&xs[(t0 + n + 0 + s_) * ROWB + cib];
        s16x8 bf1 = *(const s16x8*)&xs[(t0 + n + 2 + s_) * ROWB + cib];
        s16x8 bf2 = *(const s16x8*)&xs[(t0 + n + 4 + s_) * ROWB + cib];
        f32x4 c = {0.f, 0.f, 0.f, 0.f};
        c = __builtin_amdgcn_mfma_f32_16x16x32_bf16(afr[0], bf0, c, 0, 0, 0);
        c = __builtin_amdgcn_mfma_f32_16x16x32_bf16(afr[1], bf1, c, 0, 0, 0);
        c = __builtin_amdgcn_mfma_f32_16x16x32_bf16(afr[2], bf2, c, 0, 0, 0);
        #pragma unroll
        for (int r = 0; r < 4; ++r) { sA += c[r]; qA += c[r] * c[r]; }
    }
    for (int d = 1; d < 64; d <<= 1) {
        sA += __shfl_xor(sA, d);
        qA += __shfl_xor(qA, d);
    }
    if (l == 0) { redS[wv] = sA; redQ[wv] = qA; }
    __syncthreads();
    if (tid == 0) {
        float S = 0.f, Q = 0.f;
        for (int i = 0; i < 8; ++i) { S += redS[i]; Q += redQ[i]; }
        float* o = ws + WS_STR + ((size_t)(b * NG + g) * 2 + half) * 2;
        o[0] = S; o[1] = Q;
    }
}

// ---------------------------------------------------------------------------
// K1b: router conv -> GN -> GELU -> GAP partial per half
// ---------------------------------------------------------------------------
__global__ __launch_bounds__(512, 4) void router_apply_kernel(
    const float* __restrict__ x, const float* __restrict__ rw,
    const float* __restrict__ rg, const float* __restrict__ rb,
    float* __restrict__ ws)
{
    __shared__ short xs[NROWH * ROWB];
    __shared__ float rsum[8][CPG];

    const int bh = blockIdx.x, g = blockIdx.y;
    const int b = bh >> 1, half = bh & 1, base = half * HLF;
    const int tid = threadIdx.x;
    const int l = tid & 63, wv = tid >> 6;
    const int n = l & 15, grp = l >> 4;
    const int s_ = grp >> 1, cib = (grp & 1) * 8;

    stage_half(x + (size_t)b * CIN * T_, base, xs, tid);
    s16x8 afr[3];
    load_afrag(rw + (size_t)g * CPG * (CIN * KW), n, cib, s_, afr);

    const float* st = ws + WS_STR + (size_t)(b * NG + g) * 4;
    float S = st[0] + st[2], Q = st[1] + st[3];
    const float inv_n = 1.0f / (CPG * T_);
    float mu = S * inv_n;
    float rs = rsqrtf(Q * inv_n - mu * mu + EPS_);
    float ka[4], kb[4];
    #pragma unroll
    for (int r = 0; r < 4; ++r) {
        int co = g * CPG + grp * 4 + r;
        float gm = rg[co];
        ka[r] = rs * gm;
        kb[r] = rb[co] - mu * rs * gm;
    }
    __syncthreads();

    f32x4 tacc = {0.f, 0.f, 0.f, 0.f};
    for (int tile = 0; tile < 8; ++tile) {
        const int t0 = (wv * 8 + tile) * 16;
        s16x8 bf0 = *(const s16x8*)&xs[(t0 + n + 0 + s_) * ROWB + cib];
        s16x8 bf1 = *(const s16x8*)&xs[(t0 + n + 2 + s_) * ROWB + cib];
        s16x8 bf2 = *(const s16x8*)&xs[(t0 + n + 4 + s_) * ROWB + cib];
        f32x4 c = {0.f, 0.f, 0.f, 0.f};
        c = __builtin_amdgcn_mfma_f32_16x16x32_bf16(afr[0], bf0, c, 0, 0, 0);
        c = __builtin_amdgcn_mfma_f32_16x16x32_bf16(afr[1], bf1, c, 0, 0, 0);
        c = __builtin_amdgcn_mfma_f32_16x16x32_bf16(afr[2], bf2, c, 0, 0, 0);
        #pragma unroll
        for (int r = 0; r < 4; ++r)
            tacc[r] += gelu_fast(c[r] * ka[r] + kb[r]);
    }
    #pragma unroll
    for (int r = 0; r < 4; ++r)
        for (int d = 1; d < 16; d <<= 1)
            tacc[r] += __shfl_xor(tacc[r], d);
    if (n == 0) {
        #pragma unroll
        for (int r = 0; r < 4; ++r) rsum[wv][grp * 4 + r] = tacc[r];
    }
    __syncthreads();
    if (tid < CPG) {
        float a = 0.f;
        for (int w = 0; w < 8; ++w) a += rsum[w][tid];
        ws[WS_R0P + half * (B_ * HID) + b * HID + g * CPG + tid] = a * (1.0f / T_);
    }
}

// ---------------------------------------------------------------------------
// K2: router MLP + demo embedder + gate + softmax + top-2  (block per b)
// ---------------------------------------------------------------------------
__global__ void router_gate_kernel(
    const float* __restrict__ demo,
    const float* __restrict__ m1w, const float* __restrict__ m1b,
    const float* __restrict__ lng, const float* __restrict__ lnb,
    const float* __restrict__ m2w, const float* __restrict__ m2b,
    const float* __restrict__ d1w, const float* __restrict__ d1b,
    const float* __restrict__ dlng, const float* __restrict__ dlnb,
    const float* __restrict__ d2w, const float* __restrict__ d2b,
    const float* __restrict__ gw, const float* __restrict__ gb,
    float* __restrict__ ws)
{
    __shared__ float sh[128];
    __shared__ float dd[32];
    __shared__ float rr[80];
    __shared__ float glds[8];
    __shared__ float red[2], redq[2];

    const int b = blockIdx.x;
    const int j = threadIdx.x;
    const int lane = j & 63, wv = j >> 6;

    sh[j] = ws[WS_R0P + b * HID + j] + ws[WS_R0P + B_ * HID + b * HID + j];
    __syncthreads();

    float v = m1b[j];
    for (int i = 0; i < 128; ++i) v += sh[i] * m1w[j * 128 + i];
    float s = v, sq = v * v;
    for (int d = 1; d < 64; d <<= 1) { s += __shfl_xor(s, d); sq += __shfl_xor(sq, d); }
    if (lane == 0) { red[wv] = s; redq[wv] = sq; }
    __syncthreads();
    float S = red[0] + red[1], SQ = redq[0] + redq[1];
    float mu = S * (1.f / 128.f), var = SQ * (1.f / 128.f) - mu * mu;
    float h = (v - mu) * rsqrtf(var + EPS_) * lng[j] + lnb[j];
    float gv = gelu_erf(h);
    __syncthreads();
    sh[j] = gv;
    __syncthreads();

    if (j < 64) {
        float rv = m2b[j];
        for (int i = 0; i < 128; ++i) rv += sh[i] * m2w[j * 128 + i];
        rr[j] = rv;
    } else if (j < 96) {
        int jd = j - 64;
        float u = d1b[jd];
        for (int i = 0; i < 8; ++i) u += demo[b * 8 + i] * d1w[jd * 8 + i];
        float s2 = u, q2 = u * u;
        for (int d = 1; d < 32; d <<= 1) { s2 += __shfl_xor(s2, d, 32); q2 += __shfl_xor(q2, d, 32); }
        float mu2 = s2 * (1.f / 32.f), var2 = q2 * (1.f / 32.f) - mu2 * mu2;
        float y = (u - mu2) * rsqrtf(var2 + EPS_) * dlng[jd] + dlnb[jd];
        dd[jd] = gelu_erf(y);
    }
    __syncthreads();
    if (j < 16) {
        float rv = d2b[j];
        for (int i = 0; i < 32; ++i) rv += dd[i] * d2w[j * 32 + i];
        rr[64 + j] = rv;
    }
    __syncthreads();
    if (j < 8) {
        float lg = gb[j];
        for (int i = 0; i < 80; ++i) lg += rr[i] * gw[j * 80 + i];
        glds[j] = lg;
    }
    __syncthreads();
    if (j == 0) {
        float wsf[8];
        float m = glds[0];
        for (int e = 1; e < 8; ++e) m = fmaxf(m, glds[e]);
        float ssum = 0.f;
        for (int e = 0; e < 8; ++e) { wsf[e] = expf(glds[e] - m); ssum += wsf[e]; }
        for (int e = 0; e < 8; ++e) wsf[e] /= ssum;
        int i1 = 0;
        for (int e = 1; e < 8; ++e) if (wsf[e] > wsf[i1]) i1 = e;
        int i2 = (i1 == 0) ? 1 : 0;
        for (int e = 0; e < 8; ++e) if (e != i1 && wsf[e] > wsf[i2]) i2 = e;
        float a = wsf[i1], b2 = wsf[i2];
        float dn = a + b2 + 1e-9f;
        ws[WS_GW + b * 2 + 0] = a / dn;
        ws[WS_GW + b * 2 + 1] = b2 / dn;
        ((int*)ws)[WS_GI + b * 2 + 0] = i1;
        ((int*)ws)[WS_GI + b * 2 + 1] = i2;
    }
}

// ---------------------------------------------------------------------------
// K3a: expert conv stats partials per (b, g, slot, half)
// ---------------------------------------------------------------------------
__global__ __launch_bounds__(512, 4) void experts_stats_kernel(
    const float* __restrict__ x,
    const float* __restrict__ ew, const float* __restrict__ eb,
    const float* __restrict__ sw, const float* __restrict__ sb,
    float* __restrict__ ws)
{
    __shared__ short xs[NROWH * ROWB];
    __shared__ float redS[3][8], redQ[3][8];

    const int bh = blockIdx.x, g = blockIdx.y;
    const int b = bh >> 1, half = bh & 1, base = half * HLF;
    const int tid = threadIdx.x;
    const int l = tid & 63, wv = tid >> 6;
    const int n = l & 15, grp = l >> 4;
    const int s_ = grp >> 1, cib = (grp & 1) * 8;

    const int e1 = ((const int*)ws)[WS_GI + b * 2 + 0];
    const int e2 = ((const int*)ws)[WS_GI + b * 2 + 1];

    stage_half(x + (size_t)b * CIN * T_, base, xs, tid);

    const float* wbase[3] = {
        sw + (size_t)g * CPG * (CIN * KW),
        ew + ((size_t)e1 * 128 + g * CPG) * (CIN * KW),
        ew + ((size_t)e2 * 128 + g * CPG) * (CIN * KW) };
    s16x8 afr[3][3];
    #pragma unroll
    for (int sl = 0; sl < 3; ++sl) load_afrag(wbase[sl], n, cib, s_, afr[sl]);

    float bia[3][4];
    #pragma unroll
    for (int sl = 0; sl < 3; ++sl) {
        const float* bs = (sl == 0) ? sb : eb + ((sl == 1) ? e1 : e2) * 128;
        #pragma unroll
        for (int r = 0; r < 4; ++r) bia[sl][r] = bs[g * CPG + grp * 4 + r];
    }
    __syncthreads();

    float sA[3] = {0.f, 0.f, 0.f}, qA[3] = {0.f, 0.f, 0.f};
    for (int tile = 0; tile < 8; ++tile) {
        const int t0 = (wv * 8 + tile) * 16;
        s16x8 bf0 = *(const s16x8*)&xs[(t0 + n + 0 + s_) * ROWB + cib];
        s16x8 bf1 = *(const s16x8*)&xs[(t0 + n + 2 + s_) * ROWB + cib];
        s16x8 bf2 = *(const s16x8*)&xs[(t0 + n + 4 + s_) * ROWB + cib];
        #pragma unroll
        for (int sl = 0; sl < 3; ++sl) {
            f32x4 c = {0.f, 0.f, 0.f, 0.f};
            c = __builtin_amdgcn_mfma_f32_16x16x32_bf16(afr[sl][0], bf0, c, 0, 0, 0);
            c = __builtin_amdgcn_mfma_f32_16x16x32_bf16(afr[sl][1], bf1, c, 0, 0, 0);
            c = __builtin_amdgcn_mfma_f32_16x16x32_bf16(afr[sl][2], bf2, c, 0, 0, 0);
            #pragma unroll
            for (int r = 0; r < 4; ++r) {
                float v = c[r] + bia[sl][r];
                sA[sl] += v; qA[sl] += v * v;
            }
        }
    }
    #pragma unroll
    for (int sl = 0; sl < 3; ++sl)
        for (int d = 1; d < 64; d <<= 1) {
            sA[sl] += __shfl_xor(sA[sl], d);
            qA[sl] += __shfl_xor(qA[sl], d);
        }
    if (l == 0) {
        #pragma unroll
        for (int sl = 0; sl < 3; ++sl) { redS[sl][wv] = sA[sl]; redQ[sl][wv] = qA[sl]; }
    }
    __syncthreads();
    if (tid < 3) {
        float S = 0.f, Q = 0.f;
        for (int i = 0; i < 8; ++i) { S += redS[tid][i]; Q += redQ[tid][i]; }
        float* o = ws + WS_STE + (((size_t)(b * NG + g) * 3 + tid) * 2 + half) * 2;
        o[0] = S; o[1] = Q;
    }
}

// ---------------------------------------------------------------------------
// K3b: expert conv -> GN -> GELU -> weighted combine -> out (per half)
// ---------------------------------------------------------------------------
__global__ __launch_bounds__(512, 4) void experts_apply_kernel(
    const float* __restrict__ x,
    const float* __restrict__ ew, const float* __restrict__ eb,
    const float* __restrict__ eg, const float* __restrict__ ebt,
    const float* __restrict__ sw, const float* __restrict__ sb,
    const float* __restrict__ sg, const float* __restrict__ sbt,
    const float* __restrict__ ws, float* __restrict__ out)
{
    __shared__ short xs[NROWH * ROWB];

    const int bh = blockIdx.x, g = blockIdx.y;
    const int b = bh >> 1, half = bh & 1, base = half * HLF;
    const int tid = threadIdx.x;
    const int l = tid & 63, wv = tid >> 6;
    const int n = l & 15, grp = l >> 4;
    const int s_ = grp >> 1, cib = (grp & 1) * 8;

    const int e1 = ((const int*)ws)[WS_GI + b * 2 + 0];
    const int e2 = ((const int*)ws)[WS_GI + b * 2 + 1];
    const float scl[3] = {1.0f, ws[WS_GW + b * 2 + 0], ws[WS_GW + b * 2 + 1]};

    stage_half(x + (size_t)b * CIN * T_, base, xs, tid);

    const float* wbase[3] = {
        sw + (size_t)g * CPG * (CIN * KW),
        ew + ((size_t)e1 * 128 + g * CPG) * (CIN * KW),
        ew + ((size_t)e2 * 128 + g * CPG) * (CIN * KW) };
    s16x8 afr[3][3];
    #pragma unroll
    for (int sl = 0; sl < 3; ++sl) load_afrag(wbase[sl], n, cib, s_, afr[sl]);

    // folded epilogue: y = c*ka + kb
    const float inv_n = 1.0f / (CPG * T_);
    float ka[3][4], kb[3][4];
    #pragma unroll
    for (int sl = 0; sl < 3; ++sl) {
        const float* st = ws + WS_STE + ((size_t)(b * NG + g) * 3 + sl) * 4;
        float S = st[0] + st[2], Q = st[1] + st[3];
        float mu = S * inv_n;
        float rs = rsqrtf(Q * inv_n - mu * mu + EPS_);
        int e = (sl == 1) ? e1 : e2;
        const float* bs = (sl == 0) ? sb  : eb  + e * 128;
        const float* gs = (sl == 0) ? sg  : eg  + e * 128;
        const float* bt = (sl == 0) ? sbt : ebt + e * 128;
        #pragma unroll
        for (int r = 0; r < 4; ++r) {
            int co = g * CPG + grp * 4 + r;
            float gm = gs[co];
            ka[sl][r] = rs * gm;
            kb[sl][r] = (bs[co] - mu) * rs * gm + bt[co];
        }
    }
    __syncthreads();

    for (int tile = 0; tile < 8; ++tile) {
        const int t0 = (wv * 8 + tile) * 16;
        s16x8 bf0 = *(const s16x8*)&xs[(t0 + n + 0 + s_) * ROWB + cib];
        s16x8 bf1 = *(const s16x8*)&xs[(t0 + n + 2 + s_) * ROWB + cib];
        s16x8 bf2 = *(const s16x8*)&xs[(t0 + n + 4 + s_) * ROWB + cib];
        f32x4 oacc = {0.f, 0.f, 0.f, 0.f};
        #pragma unroll
        for (int sl = 0; sl < 3; ++sl) {
            f32x4 c = {0.f, 0.f, 0.f, 0.f};
            c = __builtin_amdgcn_mfma_f32_16x16x32_bf16(afr[sl][0], bf0, c, 0, 0, 0);
            c = __builtin_amdgcn_mfma_f32_16x16x32_bf16(afr[sl][1], bf1, c, 0, 0, 0);
            c = __builtin_amdgcn_mfma_f32_16x16x32_bf16(afr[sl][2], bf2, c, 0, 0, 0);
            #pragma unroll
            for (int r = 0; r < 4; ++r)
                oacc[r] += scl[sl] * gelu_fast(c[r] * ka[sl][r] + kb[sl][r]);
        }
        size_t obase = ((size_t)(b * 128 + g * CPG + grp * 4)) * T_ + base + t0 + n;
        #pragma unroll
        for (int r = 0; r < 4; ++r)
            out[obase + (size_t)r * T_] = oacc[r];
    }
}

// ---------------------------------------------------------------------------
extern "C" void kernel_launch(void* const* d_in, const int* in_sizes, int n_in,
                              void* d_out, int out_size, void* d_ws, size_t ws_size,
                              hipStream_t stream)
{
    const float* x    = (const float*)d_in[0];
    const float* demo = (const float*)d_in[1];
    const float* rw   = (const float*)d_in[2];
    const float* rg   = (const float*)d_in[3];
    const float* rb   = (const float*)d_in[4];
    const float* m1w  = (const float*)d_in[5];
    const float* m1b  = (const float*)d_in[6];
    const float* lng  = (const float*)d_in[7];
    const float* lnb  = (const float*)d_in[8];
    const float* m2w  = (const float*)d_in[9];
    const float* m2b  = (const float*)d_in[10];
    const float* d1w  = (const float*)d_in[11];
    const float* d1b  = (const float*)d_in[12];
    const float* dlng = (const float*)d_in[13];
    const float* dlnb = (const float*)d_in[14];
    const float* d2w  = (const float*)d_in[15];
    const float* d2b  = (const float*)d_in[16];
    const float* gw   = (const float*)d_in[17];
    const float* gb   = (const float*)d_in[18];
    const float* ew   = (const float*)d_in[19];
    const float* eb   = (const float*)d_in[20];
    const float* eg   = (const float*)d_in[21];
    const float* ebt  = (const float*)d_in[22];
    const float* sw   = (const float*)d_in[23];
    const float* sb   = (const float*)d_in[24];
    const float* sg   = (const float*)d_in[25];
    const float* sbt  = (const float*)d_in[26];
    float* out = (float*)d_out;
    float* ws  = (float*)d_ws;

    dim3 grid2(2 * B_, NG);
    router_stats_kernel<<<grid2, NTH, 0, stream>>>(x, rw, ws);
    router_apply_kernel<<<grid2, NTH, 0, stream>>>(x, rw, rg, rb, ws);
    router_gate_kernel<<<dim3(B_), 128, 0, stream>>>(
        demo, m1w, m1b, lng, lnb, m2w, m2b,
        d1w, d1b, dlng, dlnb, d2w, d2b, gw, gb, ws);
    experts_stats_kernel<<<grid2, NTH, 0, stream>>>(x, ew, eb, sw, sb, ws);
    experts_apply_kernel<<<grid2, NTH, 0, stream>>>(
        x, ew, eb, eg, ebt, sw, sb, sg, sbt, ws, out);
    (void)in_sizes; (void)n_in; (void)out_size; (void)ws_size;
}

// Round 6
// 91.944 us; speedup vs baseline: 1.4631x; 1.4631x over previous
//
#include <hip/hip_runtime.h>
#include <math.h>

#define B_    32
#define CIN   16
#define T_    2048
#define NE    8
#define NG    8
#define CPG   16
#define HID   128
#define KW    5
#define EPS_  1e-5f

#define ROWB  24      // bf16 elems per xT row (16 used + pad) -> 48B rows
#define NROW  2053    // rows t' = t+2, t in [-2, 2050]
#define NTH   1024    // 16 waves -> 4 waves/SIMD at 1 block/CU

typedef float f32x4 __attribute__((ext_vector_type(4)));
typedef short s16x8 __attribute__((ext_vector_type(8)));

__device__ __forceinline__ float gelu_fast(float y) {
    // tanh-form GELU: ~12 VALU ops vs ~30 for erff. |err| <= ~3e-3.
    float u = 0.7978845608028654f * (y + 0.044715f * y * y * y);
    float au = fabsf(u);
    float e = __expf(2.0f * au);
    float th = copysignf(1.0f - 2.0f / (e + 1.0f), u);
    return 0.5f * y * (1.0f + th);
}

__device__ __forceinline__ float gelu_erf(float y) {
    return 0.5f * y * (1.0f + erff(y * 0.70710678118654752440f));
}

__device__ __forceinline__ short bf16r(float f) {
    unsigned u = __builtin_bit_cast(unsigned, f);
    u = u + 0x7FFFu + ((u >> 16) & 1u);   // round-to-nearest-even
    return (short)(u >> 16);
}

// stage x[b] (16 x 2048 f32) -> bf16 transposed xs[t+2][ci]
__device__ __forceinline__ void stage_x(const float* __restrict__ xb,
                                        short* __restrict__ xs, int tid)
{
    for (int i = tid; i < CIN * T_; i += NTH) {
        int ci = i >> 11, t = i & 2047;
        xs[(t + 2) * ROWB + ci] = bf16r(xb[i]);
    }
    for (int i = tid; i < 5 * ROWB; i += NTH) {
        int r = i / ROWB, cc = i - r * ROWB;
        int row = (r < 2) ? r : 2048 + r;   // rows -2,-1, 2048..2050
        xs[row * ROWB + cc] = 0;
    }
}

// load one A fragment trio (3 shift-pairs) for a 16-co weight panel
__device__ __forceinline__ void load_afrag(const float* __restrict__ wb,
                                           int n, int cib, int s_, s16x8* afr)
{
    #pragma unroll
    for (int p = 0; p < 3; ++p) {
        int sh = 2 * p + s_;
        s16x8 a;
        if (sh < 5) {
            const float* wp = wb + (size_t)n * (CIN * KW) + cib * KW + sh;
            #pragma unroll
            for (int j = 0; j < 8; ++j) a[j] = bf16r(wp[j * KW]);
        } else {
            #pragma unroll
            for (int j = 0; j < 8; ++j) a[j] = 0;
        }
        afr[p] = a;
    }
}

// ---------------------------------------------------------------------------
// K1: router conv (no bias) -> GroupNorm -> GELU -> mean over T => r0 (B,128)
// block=(b,g), 1024 thr, 1 block/CU. Single conv pass, c kept in regs.
// ---------------------------------------------------------------------------
__global__ __launch_bounds__(1024, 4) void router_conv_kernel(
    const float* __restrict__ x, const float* __restrict__ rw,
    const float* __restrict__ rg, const float* __restrict__ rb,
    float* __restrict__ r0)
{
    __shared__ short xs[NROW * ROWB];
    __shared__ float redS[16], redQ[16];
    __shared__ float rsum[16][CPG];

    const int b = blockIdx.x, g = blockIdx.y;
    const int tid = threadIdx.x;
    const int l = tid & 63, wv = tid >> 6;
    const int n = l & 15, grp = l >> 4;
    const int s_ = grp >> 1, cib = (grp & 1) * 8;

    stage_x(x + (size_t)b * CIN * T_, xs, tid);
    s16x8 afr[3];
    load_afrag(rw + (size_t)g * CPG * (CIN * KW), n, cib, s_, afr);
    __syncthreads();

    // ---- conv: 8 t-tiles per wave, keep results in regs
    f32x4 cst[8];
    float sA = 0.f, qA = 0.f;
    #pragma unroll
    for (int tile = 0; tile < 8; ++tile) {
        const int t0 = (wv * 8 + tile) * 16;
        s16x8 bf0 = *(const s16x8*)&xs[(t0 + n + 0 + s_) * ROWB + cib];
        s16x8 bf1 = *(const s16x8*)&xs[(t0 + n + 2 + s_) * ROWB + cib];
        s16x8 bf2 = *(const s16x8*)&xs[(t0 + n + 4 + s_) * ROWB + cib];
        f32x4 c = {0.f, 0.f, 0.f, 0.f};
        c = __builtin_amdgcn_mfma_f32_16x16x32_bf16(afr[0], bf0, c, 0, 0, 0);
        c = __builtin_amdgcn_mfma_f32_16x16x32_bf16(afr[1], bf1, c, 0, 0, 0);
        c = __builtin_amdgcn_mfma_f32_16x16x32_bf16(afr[2], bf2, c, 0, 0, 0);
        cst[tile] = c;
        #pragma unroll
        for (int r = 0; r < 4; ++r) { sA += c[r]; qA += c[r] * c[r]; }
    }

    // ---- GN stats
    for (int d = 1; d < 64; d <<= 1) {
        sA += __shfl_xor(sA, d);
        qA += __shfl_xor(qA, d);
    }
    if (l == 0) { redS[wv] = sA; redQ[wv] = qA; }
    __syncthreads();
    float S = 0.f, Q = 0.f;
    for (int i = 0; i < 16; ++i) { S += redS[i]; Q += redQ[i]; }
    const float inv_n = 1.0f / (CPG * T_);
    float mu = S * inv_n;
    float rs = rsqrtf(Q * inv_n - mu * mu + EPS_);
    float ka[4], kb[4];
    #pragma unroll
    for (int r = 0; r < 4; ++r) {
        int co = g * CPG + grp * 4 + r;
        float gm = rg[co];
        ka[r] = rs * gm;
        kb[r] = rb[co] - mu * rs * gm;
    }

    // ---- normalize + GELU + temporal partial sums
    f32x4 tacc = {0.f, 0.f, 0.f, 0.f};
    #pragma unroll
    for (int tile = 0; tile < 8; ++tile) {
        #pragma unroll
        for (int r = 0; r < 4; ++r)
            tacc[r] += gelu_fast(cst[tile][r] * ka[r] + kb[r]);
    }
    #pragma unroll
    for (int r = 0; r < 4; ++r)
        for (int d = 1; d < 16; d <<= 1)
            tacc[r] += __shfl_xor(tacc[r], d);
    if (n == 0) {
        #pragma unroll
        for (int r = 0; r < 4; ++r) rsum[wv][grp * 4 + r] = tacc[r];
    }
    __syncthreads();
    if (tid < CPG) {
        float a = 0.f;
        for (int w = 0; w < 16; ++w) a += rsum[w][tid];
        r0[b * HID + g * CPG + tid] = a * (1.0f / T_);
    }
}

// ---------------------------------------------------------------------------
// K2: router MLP + demo embedder + gate + softmax + top-2  (block per b)
// exact erf GELU here (routing decisions must match reference)
// ---------------------------------------------------------------------------
__global__ void router_gate_kernel(
    const float* __restrict__ r0, const float* __restrict__ demo,
    const float* __restrict__ m1w, const float* __restrict__ m1b,
    const float* __restrict__ lng, const float* __restrict__ lnb,
    const float* __restrict__ m2w, const float* __restrict__ m2b,
    const float* __restrict__ d1w, const float* __restrict__ d1b,
    const float* __restrict__ dlng, const float* __restrict__ dlnb,
    const float* __restrict__ d2w, const float* __restrict__ d2b,
    const float* __restrict__ gw, const float* __restrict__ gb,
    float* __restrict__ gateW, int* __restrict__ gateI)
{
    __shared__ float sh[128];
    __shared__ float dd[32];
    __shared__ float rr[80];
    __shared__ float glds[8];
    __shared__ float red[2], redq[2];

    const int b = blockIdx.x;
    const int j = threadIdx.x;
    const int lane = j & 63, wv = j >> 6;

    sh[j] = r0[b * HID + j];
    __syncthreads();

    float v = m1b[j];
    for (int i = 0; i < 128; ++i) v += sh[i] * m1w[j * 128 + i];
    float s = v, sq = v * v;
    for (int d = 1; d < 64; d <<= 1) { s += __shfl_xor(s, d); sq += __shfl_xor(sq, d); }
    if (lane == 0) { red[wv] = s; redq[wv] = sq; }
    __syncthreads();
    float S = red[0] + red[1], SQ = redq[0] + redq[1];
    float mu = S * (1.f / 128.f), var = SQ * (1.f / 128.f) - mu * mu;
    float h = (v - mu) * rsqrtf(var + EPS_) * lng[j] + lnb[j];
    float gv = gelu_erf(h);
    __syncthreads();
    sh[j] = gv;
    __syncthreads();

    if (j < 64) {
        float rv = m2b[j];
        for (int i = 0; i < 128; ++i) rv += sh[i] * m2w[j * 128 + i];
        rr[j] = rv;
    } else if (j < 96) {
        int jd = j - 64;
        float u = d1b[jd];
        for (int i = 0; i < 8; ++i) u += demo[b * 8 + i] * d1w[jd * 8 + i];
        float s2 = u, q2 = u * u;
        for (int d = 1; d < 32; d <<= 1) { s2 += __shfl_xor(s2, d, 32); q2 += __shfl_xor(q2, d, 32); }
        float mu2 = s2 * (1.f / 32.f), var2 = q2 * (1.f / 32.f) - mu2 * mu2;
        float y = (u - mu2) * rsqrtf(var2 + EPS_) * dlng[jd] + dlnb[jd];
        dd[jd] = gelu_erf(y);
    }
    __syncthreads();
    if (j < 16) {
        float rv = d2b[j];
        for (int i = 0; i < 32; ++i) rv += dd[i] * d2w[j * 32 + i];
        rr[64 + j] = rv;
    }
    __syncthreads();
    if (j < 8) {
        float lg = gb[j];
        for (int i = 0; i < 80; ++i) lg += rr[i] * gw[j * 80 + i];
        glds[j] = lg;
    }
    __syncthreads();
    if (j == 0) {
        float wsf[8];
        float m = glds[0];
        for (int e = 1; e < 8; ++e) m = fmaxf(m, glds[e]);
        float ssum = 0.f;
        for (int e = 0; e < 8; ++e) { wsf[e] = expf(glds[e] - m); ssum += wsf[e]; }
        for (int e = 0; e < 8; ++e) wsf[e] /= ssum;
        int i1 = 0;
        for (int e = 1; e < 8; ++e) if (wsf[e] > wsf[i1]) i1 = e;
        int i2 = (i1 == 0) ? 1 : 0;
        for (int e = 0; e < 8; ++e) if (e != i1 && wsf[e] > wsf[i2]) i2 = e;
        float a = wsf[i1], b2 = wsf[i2];
        float dn = a + b2 + 1e-9f;
        gateW[b * 2 + 0] = a / dn;
        gateW[b * 2 + 1] = b2 / dn;
        gateI[b * 2 + 0] = i1;
        gateI[b * 2 + 1] = i2;
    }
}

// ---------------------------------------------------------------------------
// K3: shared + top-2 experts: conv -> GN -> GELU -> weighted sum -> out
// block=(b,g), 1024 thr, 1 block/CU. pass1 stats, pass2 folded epilogue.
// ---------------------------------------------------------------------------
__global__ __launch_bounds__(1024, 4) void experts_kernel(
    const float* __restrict__ x,
    const float* __restrict__ ew, const float* __restrict__ eb,
    const float* __restrict__ eg, const float* __restrict__ ebt,
    const float* __restrict__ sw, const float* __restrict__ sb,
    const float* __restrict__ sg, const float* __restrict__ sbt,
    const float* __restrict__ gateW, const int* __restrict__ gateI,
    float* __restrict__ out)
{
    __shared__ short xs[NROW * ROWB];
    __shared__ float redS[3][16], redQ[3][16];

    const int b = blockIdx.x, g = blockIdx.y;
    const int tid = threadIdx.x;
    const int l = tid & 63, wv = tid >> 6;
    const int n = l & 15, grp = l >> 4;
    const int s_ = grp >> 1, cib = (grp & 1) * 8;

    const int e1 = gateI[b * 2 + 0], e2 = gateI[b * 2 + 1];
    const float scl[3] = {1.0f, gateW[b * 2 + 0], gateW[b * 2 + 1]};

    stage_x(x + (size_t)b * CIN * T_, xs, tid);

    const float* wbase[3] = {
        sw + (size_t)g * CPG * (CIN * KW),
        ew + ((size_t)e1 * 128 + g * CPG) * (CIN * KW),
        ew + ((size_t)e2 * 128 + g * CPG) * (CIN * KW) };
    s16x8 afr[3][3];
    #pragma unroll
    for (int sl = 0; sl < 3; ++sl) load_afrag(wbase[sl], n, cib, s_, afr[sl]);

    float bia[3][4];
    #pragma unroll
    for (int sl = 0; sl < 3; ++sl) {
        const float* bs = (sl == 0) ? sb : eb + ((sl == 1) ? e1 : e2) * 128;
        #pragma unroll
        for (int r = 0; r < 4; ++r) bia[sl][r] = bs[g * CPG + grp * 4 + r];
    }
    __syncthreads();

    // ---- pass 1: conv -> stats only
    float sA[3] = {0.f, 0.f, 0.f}, qA[3] = {0.f, 0.f, 0.f};
    for (int tile = 0; tile < 8; ++tile) {
        const int t0 = (wv * 8 + tile) * 16;
        s16x8 bf0 = *(const s16x8*)&xs[(t0 + n + 0 + s_) * ROWB + cib];
        s16x8 bf1 = *(const s16x8*)&xs[(t0 + n + 2 + s_) * ROWB + cib];
        s16x8 bf2 = *(const s16x8*)&xs[(t0 + n + 4 + s_) * ROWB + cib];
        #pragma unroll
        for (int sl = 0; sl < 3; ++sl) {
            f32x4 c = {0.f, 0.f, 0.f, 0.f};
            c = __builtin_amdgcn_mfma_f32_16x16x32_bf16(afr[sl][0], bf0, c, 0, 0, 0);
            c = __builtin_amdgcn_mfma_f32_16x16x32_bf16(afr[sl][1], bf1, c, 0, 0, 0);
            c = __builtin_amdgcn_mfma_f32_16x16x32_bf16(afr[sl][2], bf2, c, 0, 0, 0);
            #pragma unroll
            for (int r = 0; r < 4; ++r) {
                float v = c[r] + bia[sl][r];
                sA[sl] += v; qA[sl] += v * v;
            }
        }
    }
    #pragma unroll
    for (int sl = 0; sl < 3; ++sl)
        for (int d = 1; d < 64; d <<= 1) {
            sA[sl] += __shfl_xor(sA[sl], d);
            qA[sl] += __shfl_xor(qA[sl], d);
        }
    if (l == 0) {
        #pragma unroll
        for (int sl = 0; sl < 3; ++sl) { redS[sl][wv] = sA[sl]; redQ[sl][wv] = qA[sl]; }
    }
    __syncthreads();

    // folded epilogue constants: y = c*ka + kb
    const float inv_n = 1.0f / (CPG * T_);
    float ka[3][4], kb[3][4];
    #pragma unroll
    for (int sl = 0; sl < 3; ++sl) {
        float S = 0.f, Q = 0.f;
        for (int i = 0; i < 16; ++i) { S += redS[sl][i]; Q += redQ[sl][i]; }
        float mu = S * inv_n;
        float rs = rsqrtf(Q * inv_n - mu * mu + EPS_);
        int e = (sl == 1) ? e1 : e2;
        const float* gs = (sl == 0) ? sg  : eg  + e * 128;
        const float* bt = (sl == 0) ? sbt : ebt + e * 128;
        #pragma unroll
        for (int r = 0; r < 4; ++r) {
            int co = g * CPG + grp * 4 + r;
            float gm = gs[co];
            ka[sl][r] = rs * gm;
            kb[sl][r] = (bia[sl][r] - mu) * rs * gm + bt[co];
        }
    }

    // ---- pass 2: recompute conv, folded GN + fast GELU + combine, store
    for (int tile = 0; tile < 8; ++tile) {
        const int t0 = (wv * 8 + tile) * 16;
        s16x8 bf0 = *(const s16x8*)&xs[(t0 + n + 0 + s_) * ROWB + cib];
        s16x8 bf1 = *(const s16x8*)&xs[(t0 + n + 2 + s_) * ROWB + cib];
        s16x8 bf2 = *(const s16x8*)&xs[(t0 + n + 4 + s_) * ROWB + cib];
        f32x4 oacc = {0.f, 0.f, 0.f, 0.f};
        #pragma unroll
        for (int sl = 0; sl < 3; ++sl) {
            f32x4 c = {0.f, 0.f, 0.f, 0.f};
            c = __builtin_amdgcn_mfma_f32_16x16x32_bf16(afr[sl][0], bf0, c, 0, 0, 0);
            c = __builtin_amdgcn_mfma_f32_16x16x32_bf16(afr[sl][1], bf1, c, 0, 0, 0);
            c = __builtin_amdgcn_mfma_f32_16x16x32_bf16(afr[sl][2], bf2, c, 0, 0, 0);
            #pragma unroll
            for (int r = 0; r < 4; ++r)
                oacc[r] += scl[sl] * gelu_fast(c[r] * ka[sl][r] + kb[sl][r]);
        }
        size_t obase = ((size_t)(b * 128 + g * CPG + grp * 4)) * T_ + t0 + n;
        #pragma unroll
        for (int r = 0; r < 4; ++r)
            out[obase + (size_t)r * T_] = oacc[r];
    }
}

// ---------------------------------------------------------------------------
extern "C" void kernel_launch(void* const* d_in, const int* in_sizes, int n_in,
                              void* d_out, int out_size, void* d_ws, size_t ws_size,
                              hipStream_t stream)
{
    const float* x    = (const float*)d_in[0];
    const float* demo = (const float*)d_in[1];
    const float* rw   = (const float*)d_in[2];
    const float* rg   = (const float*)d_in[3];
    const float* rb   = (const float*)d_in[4];
    const float* m1w  = (const float*)d_in[5];
    const float* m1b  = (const float*)d_in[6];
    const float* lng  = (const float*)d_in[7];
    const float* lnb  = (const float*)d_in[8];
    const float* m2w  = (const float*)d_in[9];
    const float* m2b  = (const float*)d_in[10];
    const float* d1w  = (const float*)d_in[11];
    const float* d1b  = (const float*)d_in[12];
    const float* dlng = (const float*)d_in[13];
    const float* dlnb = (const float*)d_in[14];
    const float* d2w  = (const float*)d_in[15];
    const float* d2b  = (const float*)d_in[16];
    const float* gw   = (const float*)d_in[17];
    const float* gb   = (const float*)d_in[18];
    const float* ew   = (const float*)d_in[19];
    const float* eb   = (const float*)d_in[20];
    const float* eg   = (const float*)d_in[21];
    const float* ebt  = (const float*)d_in[22];
    const float* sw   = (const float*)d_in[23];
    const float* sb   = (const float*)d_in[24];
    const float* sg   = (const float*)d_in[25];
    const float* sbt  = (const float*)d_in[26];
    float* out = (float*)d_out;

    float* r0    = (float*)d_ws;
    float* gateW = r0 + B_ * HID;
    int*   gateI = (int*)(gateW + 64);

    dim3 gridc(B_, NG);   // b fastest -> all 8 g-blocks of one b share an XCD
    router_conv_kernel<<<gridc, NTH, 0, stream>>>(x, rw, rg, rb, r0);
    router_gate_kernel<<<dim3(B_), 128, 0, stream>>>(
        r0, demo, m1w, m1b, lng, lnb, m2w, m2b,
        d1w, d1b, dlng, dlnb, d2w, d2b, gw, gb, gateW, gateI);
    experts_kernel<<<gridc, NTH, 0, stream>>>(
        x, ew, eb, eg, ebt, sw, sb, sg, sbt, gateW, gateI, out);
    (void)in_sizes; (void)n_in; (void)out_size; (void)ws_size;
}